// Round 10
// baseline (1219.408 us; speedup 1.0000x reference)
//
#include <hip/hip_runtime.h>
#include <cstdint>
#include <cstddef>

#define HID 512
#define BATCH 4096
#define T_STEPS 20

typedef unsigned short ushort_t;
typedef __attribute__((ext_vector_type(8))) __bf16 bf16x8;
typedef __attribute__((ext_vector_type(4))) float f32x4;

// fp32 -> bf16 round-to-nearest-even (finite inputs only)
__device__ __forceinline__ unsigned short f2bf(float f) {
  unsigned int u = __float_as_uint(f);
  u += 0x7FFFu + ((u >> 16) & 1u);
  return (unsigned short)(u >> 16);
}

// 1-ulp hardware reciprocal (v_rcp_f32)
__device__ __forceinline__ float frcp(float x) {
  float r; asm("v_rcp_f32 %0, %1" : "=v"(r) : "v"(x)); return r;
}
__device__ __forceinline__ float fsigm(float x) { return frcp(1.f + __expf(-x)); }
__device__ __forceinline__ float ftanh(float x) { return 1.f - 2.f * frcp(__expf(2.f * x) + 1.f); }

// direct global->VGPR 16B load: saddr base + per-lane 32-bit byte offset.
// volatile => issue order is program order (deterministic pipeline).
__device__ __forceinline__ bf16x8 gload(const ushort_t* base, int voff) {
  bf16x8 r;
  asm volatile("global_load_dwordx4 %0, %1, %2"
               : "=v"(r) : "v"(voff), "s"(base) : "memory");
  return r;
}

// counted vmcnt waits; sched_barrier stops MFMA hoisting past the wait (rule #18)
#define WAIT12 do { asm volatile("s_waitcnt vmcnt(12)" ::: "memory"); __builtin_amdgcn_sched_barrier(0); } while (0)
#define WAIT8  do { asm volatile("s_waitcnt vmcnt(8)"  ::: "memory"); __builtin_amdgcn_sched_barrier(0); } while (0)
#define WAIT6  do { asm volatile("s_waitcnt vmcnt(6)"  ::: "memory"); __builtin_amdgcn_sched_barrier(0); } while (0)
#define WAIT4  do { asm volatile("s_waitcnt vmcnt(4)"  ::: "memory"); __builtin_amdgcn_sched_barrier(0); } while (0)
#define WAIT0  do { asm volatile("s_waitcnt vmcnt(0)"  ::: "memory"); __builtin_amdgcn_sched_barrier(0); } while (0)

// ---------------------------------------------------------------------------
// PERSISTENT fused ODE kernel — B-operands DIRECT global->VGPR (no LDS pass).
// Rounds 8/9 pinned at ~34us/step: weights crossed the LDS pipe twice
// (2MB DMA-write + 2.2MB ds_read per step per CU ~= 18us of LDS occupancy).
// Each wave's B-slice is consumed exactly once by that wave -> zero reuse ->
// LDS staging was pure overhead. The mfma B-fragment (B[n=lane&15][k=quad*8+e])
// is exactly one 16B global load per lane; 4 quads cover a 64B line.
// Pipeline: 3-slot register ring per GEMM, manual counted vmcnt
// (steady 12/8, drain only at phase end), issue-after-consume ordering.
// GEMM1->GEMM2 handoff: raw lgkmcnt(0)+s_barrier so GEMM2's prologue loads
// stay in flight across it. LDS now only zbs/dhs/reductions (35KB).
// MFMA order / activation / epilogue verbatim round 9 (absmax 0.0).
// ---------------------------------------------------------------------------
__global__ __launch_bounds__(512) void ode_persistent(
    const float* __restrict__ y,
    const ushort_t* __restrict__ Wcat,   // [3*512,512] bf16 row-major
    const ushort_t* __restrict__ WoutB,  // [512,512] bf16 row-major
    const float* __restrict__ bout,
    const float* __restrict__ Wfc, const float* __restrict__ bfc,
    const float* __restrict__ ts, float* __restrict__ out) {
  __shared__ ushort_t zbs[64 * 16 * 8];     // 16 KB  [kp][row][e] bf16(z)
  __shared__ ushort_t dhs[64 * 16 * 8];     // 16 KB  [kp][row][e] dh
  __shared__ float rmax1[8][16];
  __shared__ float rsum1[8][16];
  __shared__ float rmax2[8][16];
  __shared__ float rsd[8][16][2];
  __shared__ float dts[T_STEPS];

  const int tid = threadIdx.x;
  const int wave = tid >> 6;     // 0..7
  const int lane = tid & 63;
  const int quad = lane >> 4;
  const int l16 = lane & 15;
  const int m0 = blockIdx.x * 16;
  const int wn2 = wave * 64;     // epilogue/GEMM2 column base

  if (tid < T_STEPS - 1) dts[tid] = ts[tid + 1] - ts[tid];

  // constants per thread
  float boutr[4], wfcr[4];
#pragma unroll
  for (int j = 0; j < 4; ++j) {
    boutr[j] = bout[wn2 + j * 16 + l16];
    wfcr[j] = Wfc[wn2 + j * 16 + l16];
  }
  const float bfc0 = bfc[0];

  // --- per-lane B-load byte offsets (computed once) ---
  // GEMM1 i = gate*2 + half: W row (gate*512 + ht*128 + wave*16 + l16),
  //   k = half*32 + quad*8 ; group delta adds ht*131072 + kk*128 bytes
  int voff1[6];
#pragma unroll
  for (int i = 0; i < 6; ++i) {
    int gate = i >> 1, half = i & 1;
    voff1[i] = 2 * (gate * 262144 + (wave * 16 + l16) * 512 + half * 32 + quad * 8);
  }
  // GEMM2 j: W row (wave*64 + j*16 + l16), k = quad*8 ; delta = tt*64 bytes
  int voff2[4];
#pragma unroll
  for (int j = 0; j < 4; ++j)
    voff2[j] = 2 * ((wave * 64 + j * 16 + l16) * 512 + quad * 8);

  // z state: z[row=quad*4+r][col=wn2+j*16+l16] = zreg[j][r]
  f32x4 zreg[4];
#pragma unroll
  for (int j = 0; j < 4; ++j) {
    int col = wn2 + j * 16 + l16;
    int kp = col >> 3, ce = col & 7;
#pragma unroll
    for (int r = 0; r < 4; ++r) {
      float v = y[(size_t)(m0 + quad * 4 + r) * HID + col];
      zreg[j][r] = v;
      zbs[(kp * 16 + quad * 4 + r) * 8 + ce] = f2bf(v);
    }
  }

  auto proj_out = [&](int tcol) {
    float m2[4];
#pragma unroll
    for (int r = 0; r < 4; ++r) {
      float m = zreg[0][r];
#pragma unroll
      for (int j = 1; j < 4; ++j) m = fmaxf(m, zreg[j][r]);
#pragma unroll
      for (int off = 1; off < 16; off <<= 1) m = fmaxf(m, __shfl_xor(m, off));
      m2[r] = m;
    }
    if (l16 == 0) {
#pragma unroll
      for (int r = 0; r < 4; ++r) rmax2[wave][quad * 4 + r] = m2[r];
    }
    __syncthreads();
#pragma unroll
    for (int r = 0; r < 4; ++r) {
      int row = quad * 4 + r;
      float m = rmax2[0][row];
#pragma unroll
      for (int w = 1; w < 8; ++w) m = fmaxf(m, rmax2[w][row]);
      m2[r] = m;
    }
    float s2[4] = {0.f, 0.f, 0.f, 0.f};
    float dd[4] = {0.f, 0.f, 0.f, 0.f};
#pragma unroll
    for (int j = 0; j < 4; ++j)
#pragma unroll
      for (int r = 0; r < 4; ++r) {
        float e = __expf(zreg[j][r] - m2[r]);
        s2[r] += e;
        dd[r] += e * wfcr[j];
      }
#pragma unroll
    for (int r = 0; r < 4; ++r) {
#pragma unroll
      for (int off = 1; off < 16; off <<= 1) {
        s2[r] += __shfl_xor(s2[r], off);
        dd[r] += __shfl_xor(dd[r], off);
      }
    }
    if (l16 == 0) {
#pragma unroll
      for (int r = 0; r < 4; ++r) {
        rsd[wave][quad * 4 + r][0] = s2[r];
        rsd[wave][quad * 4 + r][1] = dd[r];
      }
    }
    __syncthreads();
    if (wave == 0 && l16 == 0) {
#pragma unroll
      for (int r = 0; r < 4; ++r) {
        int row = quad * 4 + r;
        float ss = 0.f, dv = 0.f;
#pragma unroll
        for (int w = 0; w < 8; ++w) { ss += rsd[w][row][0]; dv += rsd[w][row][1]; }
        out[(size_t)(m0 + row) * T_STEPS + tcol] = dv / ss + bfc0;
      }
    }
    __syncthreads();
  };

  proj_out(0);

  // ======================= time loop =======================
  for (int t = 0; t < T_STEPS - 1; ++t) {
    // ---- A-fragments for the step: 16 statically-indexed regs ----
    bf16x8 afr[16];
#pragma unroll
    for (int kk = 0; kk < 8; ++kk) {
      afr[2 * kk]     = *(const bf16x8*)&zbs[((kk * 8 + quad) * 16 + l16) * 8];
      afr[2 * kk + 1] = *(const bf16x8*)&zbs[((kk * 8 + 4 + quad) * 16 + l16) * 8];
    }

    // ---- GEMM1: 32 groups (ht*8+kk), 3-slot B ring, direct loads ----
    bf16x8 bb[3][6];
#pragma unroll
    for (int p = 0; p < 3; ++p) {
      const int d = (p >> 3) * 131072 + (p & 7) * 128;
#pragma unroll
      for (int i = 0; i < 6; ++i) bb[p][i] = gload(Wcat, voff1[i] + d);
    }
    f32x4 a0 = {}, a1 = {}, a2 = {};
#pragma unroll
    for (int g = 0; g < 32; ++g) {
      const int kk = g & 7;
      if (kk == 0) { a0 = f32x4{}; a1 = f32x4{}; a2 = f32x4{}; }
      if (g <= 29) { WAIT12; } else if (g == 30) { WAIT6; } else { WAIT0; }
      {
        bf16x8* s = bb[g % 3];
        a0 = __builtin_amdgcn_mfma_f32_16x16x32_bf16(afr[2 * kk],     s[0], a0, 0, 0, 0);
        a0 = __builtin_amdgcn_mfma_f32_16x16x32_bf16(afr[2 * kk + 1], s[1], a0, 0, 0, 0);
        a1 = __builtin_amdgcn_mfma_f32_16x16x32_bf16(afr[2 * kk],     s[2], a1, 0, 0, 0);
        a1 = __builtin_amdgcn_mfma_f32_16x16x32_bf16(afr[2 * kk + 1], s[3], a1, 0, 0, 0);
        a2 = __builtin_amdgcn_mfma_f32_16x16x32_bf16(afr[2 * kk],     s[4], a2, 0, 0, 0);
        a2 = __builtin_amdgcn_mfma_f32_16x16x32_bf16(afr[2 * kk + 1], s[5], a2, 0, 0, 0);
      }
      if (g + 3 < 32) {   // refill the slot just consumed
        const int n = g + 3;
        const int d = (n >> 3) * 131072 + (n & 7) * 128;
        bf16x8* s = bb[n % 3];
#pragma unroll
        for (int i = 0; i < 6; ++i) s[i] = gload(Wcat, voff1[i] + d);
      }
      if (kk == 7) {
        // activation -> dhs (wave's own cols: ht*128 + wave*16 + l16)
        int col = (g >> 3) * 128 + wave * 16 + l16;
        int kp = col >> 3, ce = col & 7;
#pragma unroll
        for (int r = 0; r < 4; ++r) {
          float gi = fsigm(a0[r]);
          float gg = ftanh(a1[r]);
          float go = fsigm(a2[r]);
          dhs[(kp * 16 + quad * 4 + r) * 8 + ce] = f2bf(go * ftanh(gi * gg));
        }
      }
    }

    // ---- GEMM2 prologue issued BEFORE the dhs barrier (loads don't touch dhs);
    //      raw lgkmcnt(0)+s_barrier leaves the 12 loads in flight ----
    bf16x8 b2[3][4];
#pragma unroll
    for (int p = 0; p < 3; ++p) {
#pragma unroll
      for (int j = 0; j < 4; ++j) b2[p][j] = gload(WoutB, voff2[j] + p * 64);
    }
    asm volatile("s_waitcnt lgkmcnt(0)\n\ts_barrier" ::: "memory");
    __builtin_amdgcn_sched_barrier(0);

    // ---- GEMM2: 16 groups, 3-slot ring ----
    f32x4 acc2[4] = {};
#pragma unroll
    for (int g = 0; g < 16; ++g) {
      if (g <= 13) { WAIT8; } else if (g == 14) { WAIT4; } else { WAIT0; }
      bf16x8 afd = *(const bf16x8*)&dhs[((g * 4 + quad) * 16 + l16) * 8];
      {
        bf16x8* s = b2[g % 3];
        acc2[0] = __builtin_amdgcn_mfma_f32_16x16x32_bf16(afd, s[0], acc2[0], 0, 0, 0);
        acc2[1] = __builtin_amdgcn_mfma_f32_16x16x32_bf16(afd, s[1], acc2[1], 0, 0, 0);
        acc2[2] = __builtin_amdgcn_mfma_f32_16x16x32_bf16(afd, s[2], acc2[2], 0, 0, 0);
        acc2[3] = __builtin_amdgcn_mfma_f32_16x16x32_bf16(afd, s[3], acc2[3], 0, 0, 0);
      }
      if (g + 3 < 16) {
        const int n = g + 3;
        bf16x8* s = b2[n % 3];
#pragma unroll
        for (int j = 0; j < 4; ++j) s[j] = gload(WoutB, voff2[j] + n * 64);
      }
    }

    // ---- epilogue (verbatim): softmax(+bout), z += dt*s, zbs refresh ----
    const float dtv = dts[t];
#pragma unroll
    for (int j = 0; j < 4; ++j)
#pragma unroll
      for (int r = 0; r < 4; ++r) acc2[j][r] += boutr[j];

    float m1[4];
#pragma unroll
    for (int r = 0; r < 4; ++r) {
      float m = acc2[0][r];
#pragma unroll
      for (int j = 1; j < 4; ++j) m = fmaxf(m, acc2[j][r]);
#pragma unroll
      for (int off = 1; off < 16; off <<= 1) m = fmaxf(m, __shfl_xor(m, off));
      m1[r] = m;
    }
    if (l16 == 0) {
#pragma unroll
      for (int r = 0; r < 4; ++r) rmax1[wave][quad * 4 + r] = m1[r];
    }
    __syncthreads();
#pragma unroll
    for (int r = 0; r < 4; ++r) {
      int row = quad * 4 + r;
      float m = rmax1[0][row];
#pragma unroll
      for (int w = 1; w < 8; ++w) m = fmaxf(m, rmax1[w][row]);
      m1[r] = m;
    }

    float s1[4] = {0.f, 0.f, 0.f, 0.f};
#pragma unroll
    for (int j = 0; j < 4; ++j)
#pragma unroll
      for (int r = 0; r < 4; ++r) {
        float e = __expf(acc2[j][r] - m1[r]);
        acc2[j][r] = e;
        s1[r] += e;
      }
#pragma unroll
    for (int r = 0; r < 4; ++r) {
#pragma unroll
      for (int off = 1; off < 16; off <<= 1) s1[r] += __shfl_xor(s1[r], off);
    }
    if (l16 == 0) {
#pragma unroll
      for (int r = 0; r < 4; ++r) rsum1[wave][quad * 4 + r] = s1[r];
    }
    __syncthreads();
    float inv1[4];
#pragma unroll
    for (int r = 0; r < 4; ++r) {
      int row = quad * 4 + r;
      float s = rsum1[0][row];
#pragma unroll
      for (int w = 1; w < 8; ++w) s += rsum1[w][row];
      inv1[r] = 1.f / s;
    }

#pragma unroll
    for (int j = 0; j < 4; ++j) {
      int col = wn2 + j * 16 + l16;
      int kp = col >> 3, ce = col & 7;
#pragma unroll
      for (int r = 0; r < 4; ++r) {
        float zn = zreg[j][r] + dtv * acc2[j][r] * inv1[r];
        zreg[j][r] = zn;
        zbs[(kp * 16 + quad * 4 + r) * 8 + ce] = f2bf(zn);
      }
    }

    proj_out(t + 1);   // ends with __syncthreads: zbs visible for next GEMM1
  }
}

// weights fp32 -> bf16; Wcat = [Wi; Wg; Wo] (each 512x512, row-major => flat concat)
__global__ __launch_bounds__(256) void convw_kernel(
    const float* __restrict__ Wi, const float* __restrict__ Wg,
    const float* __restrict__ Wo, const float* __restrict__ Wout,
    ushort_t* __restrict__ Wcat, ushort_t* __restrict__ WoutB) {
  const int nW = HID * HID;  // 262144
  int e = (blockIdx.x * 256 + threadIdx.x) * 4;  // 1024 blocks covers 4*nW
  const float* src;
  ushort_t* dst;
  if (e < nW)            { src = Wi + e;          dst = Wcat + e; }
  else if (e < 2 * nW)   { src = Wg + (e - nW);   dst = Wcat + e; }
  else if (e < 3 * nW)   { src = Wo + (e - 2*nW); dst = Wcat + e; }
  else                   { src = Wout + (e - 3*nW); dst = WoutB + (e - 3*nW); }
  float4 v = *(const float4*)src;
  union { unsigned short us[4]; uint2 u; } p;
  p.us[0] = f2bf(v.x); p.us[1] = f2bf(v.y); p.us[2] = f2bf(v.z); p.us[3] = f2bf(v.w);
  *(uint2*)dst = p.u;
}

extern "C" void kernel_launch(void* const* d_in, const int* in_sizes, int n_in,
                              void* d_out, int out_size, void* d_ws, size_t ws_size,
                              hipStream_t stream) {
  const float* y    = (const float*)d_in[0];
  const float* ts   = (const float*)d_in[1];
  const float* Wi   = (const float*)d_in[2];
  // d_in[3] = Wf: computed-but-unused in reference -> skipped
  const float* Wg   = (const float*)d_in[4];
  const float* Wo   = (const float*)d_in[5];
  const float* Wout = (const float*)d_in[6];
  const float* bout = (const float*)d_in[7];
  const float* Wfc  = (const float*)d_in[8];
  const float* bfc  = (const float*)d_in[9];
  float* out = (float*)d_out;

  // workspace: only converted weights
  char* ws = (char*)d_ws;
  ushort_t* Wcat  = (ushort_t*)(ws);             // 1536*512*2 = 1572864
  ushort_t* WoutB = (ushort_t*)(ws + 1572864);   // 512*512*2  = 524288

  convw_kernel<<<1024, 256, 0, stream>>>(Wi, Wg, Wo, Wout, Wcat, WoutB);
  // ONE persistent kernel; B-operands direct global->VGPR, counted-vmcnt ring.
  ode_persistent<<<256, 512, 0, stream>>>(y, Wcat, WoutB, bout, Wfc, bfc, ts, out);
}